// Round 8
// baseline (287.407 us; speedup 1.0000x reference)
//
#include <hip/hip_runtime.h>
#include <math.h>

// GATv2Regressor: N=100k nodes, E=1.6M edges (+N self-loops), F=128, C=32, H1=2, G=64.
// CSR-by-dst GAT layers, no-max softmax, multi-edge-per-wave with DPP sub-group reductions;
// gather tables (xl) stored bf16 (halves L3-fill on random gathers); CSR via bucket
// partition; dense transforms via 32-row LDS-tiled dual-weight GEMMs (occupancy-tuned).

constexpr float NEG_SLOPE = 0.2f;

// DPP helpers: quad_perm xor1 = 0xB1, xor2 = 0x4E, row_half_mirror = 0x141.
#define DPP_ADD(v, ctrl)                                                             \
  do {                                                                               \
    int _t = __builtin_amdgcn_update_dpp(0, __float_as_int(v), (ctrl), 0xF, 0xF, true); \
    (v) = (v) + __int_as_float(_t);                                                  \
  } while (0)
#define REDUCE8(v) do { DPP_ADD(v, 0xB1); DPP_ADD(v, 0x4E); DPP_ADD(v, 0x141); } while (0)

__device__ __forceinline__ unsigned short f2bf(float f) {   // RNE f32 -> bf16
  unsigned u = __float_as_uint(f);
  return (unsigned short)((u + 0x7FFFu + ((u >> 16) & 1u)) >> 16);
}
__device__ __forceinline__ float bf2f(unsigned short h) {   // exact bf16 -> f32
  return __uint_as_float(((unsigned)h) << 16);
}

// ---------------- dense: 32-row LDS-tiled dual-weight GEMM ----------------
// out{l,r}[n][NH] = x[n][K] @ W{l,r}[K][NH] + b{l,r}.  outl is bf16 (gather table), outr f32.
template<int K, int NH>
__global__ __launch_bounds__(256) void mm_dual_kernel(const float* __restrict__ x,
    const float* __restrict__ Wl, const float* __restrict__ bl,
    const float* __restrict__ Wr, const float* __restrict__ br,
    unsigned short* __restrict__ outl, float* __restrict__ outr, int n)
{
  constexpr int CGT = NH / 2;         // total 4-col groups (both weights)
  constexpr int RG  = 256 / CGT;      // row groups
  constexpr int RPT = 32 / RG;        // rows per thread
  constexpr int LPT = (32 * K / 4) / 256;  // float4 staging loads per thread
  __shared__ float xs[32 * K];
  const int t = threadIdx.x;
  const int rowbase = blockIdx.x * 32;

#pragma unroll
  for (int j = 0; j < LPT; ++j) {
    int idx4 = t + j * 256;
    int r  = idx4 / (K / 4);
    int c4 = idx4 % (K / 4);
    int row = rowbase + r;
    float4 v = make_float4(0.f, 0.f, 0.f, 0.f);
    if (row < n) v = *(const float4*)&x[(size_t)row * K + c4 * 4];
    *(float4*)&xs[r * K + c4 * 4] = v;
  }
  __syncthreads();

  const int cg = t % CGT, rg = t / CGT;
  const bool hi = cg >= (CGT / 2);
  const float* W = hi ? Wr : Wl;
  const float* B = hi ? br : bl;
  const int colb = (hi ? (cg - CGT / 2) : cg) * 4;

  float acc[RPT][4];
#pragma unroll
  for (int r = 0; r < RPT; ++r) acc[r][0] = acc[r][1] = acc[r][2] = acc[r][3] = 0.f;

  const float* wp = W + colb;
#pragma unroll 2
  for (int k0 = 0; k0 < K; k0 += 4) {
    float4 w0 = *(const float4*)&wp[(size_t)(k0 + 0) * NH];
    float4 w1 = *(const float4*)&wp[(size_t)(k0 + 1) * NH];
    float4 w2 = *(const float4*)&wp[(size_t)(k0 + 2) * NH];
    float4 w3 = *(const float4*)&wp[(size_t)(k0 + 3) * NH];
#pragma unroll
    for (int r = 0; r < RPT; ++r) {
      float4 xv = *(const float4*)&xs[(rg * RPT + r) * K + k0];   // ds_read_b128
      acc[r][0] = fmaf(xv.x, w0.x, acc[r][0]);
      acc[r][1] = fmaf(xv.x, w0.y, acc[r][1]);
      acc[r][2] = fmaf(xv.x, w0.z, acc[r][2]);
      acc[r][3] = fmaf(xv.x, w0.w, acc[r][3]);
      acc[r][0] = fmaf(xv.y, w1.x, acc[r][0]);
      acc[r][1] = fmaf(xv.y, w1.y, acc[r][1]);
      acc[r][2] = fmaf(xv.y, w1.z, acc[r][2]);
      acc[r][3] = fmaf(xv.y, w1.w, acc[r][3]);
      acc[r][0] = fmaf(xv.z, w2.x, acc[r][0]);
      acc[r][1] = fmaf(xv.z, w2.y, acc[r][1]);
      acc[r][2] = fmaf(xv.z, w2.z, acc[r][2]);
      acc[r][3] = fmaf(xv.z, w2.w, acc[r][3]);
      acc[r][0] = fmaf(xv.w, w3.x, acc[r][0]);
      acc[r][1] = fmaf(xv.w, w3.y, acc[r][1]);
      acc[r][2] = fmaf(xv.w, w3.z, acc[r][2]);
      acc[r][3] = fmaf(xv.w, w3.w, acc[r][3]);
    }
  }
  float4 bv = *(const float4*)&B[colb];
#pragma unroll
  for (int r = 0; r < RPT; ++r) {
    int row = rowbase + rg * RPT + r;
    if (row < n) {
      float o0 = acc[r][0] + bv.x, o1 = acc[r][1] + bv.y;
      float o2 = acc[r][2] + bv.z, o3 = acc[r][3] + bv.w;
      if (hi) {
        float4 o = make_float4(o0, o1, o2, o3);
        *(float4*)&outr[(size_t)row * NH + colb] = o;
      } else {
        ushort4 h;
        h.x = f2bf(o0); h.y = f2bf(o1); h.z = f2bf(o2); h.w = f2bf(o3);
        *(ushort4*)&outl[(size_t)row * NH + colb] = h;
      }
    }
  }
}

// gate[n] = relu(h2 @ Wg1 + bg1) @ Wg2 + bg2 (fused, thread-per-row)
__global__ __launch_bounds__(256) void gate_kernel(const float* __restrict__ h2,
    const float* __restrict__ Wg1, const float* __restrict__ bg1,
    const float* __restrict__ Wg2, const float* __restrict__ bg2,
    float* __restrict__ gate, int n)
{
  int row = blockIdx.x * 256 + threadIdx.x;
  int rr = (row < n) ? row : 0;
  const float* hp = h2 + (size_t)rr * 32;
  float acc[32];
#pragma unroll
  for (int c = 0; c < 32; ++c) acc[c] = 0.f;
  for (int k0 = 0; k0 < 32; k0 += 8) {
    float4 a0 = *(const float4*)(hp + k0 + 0);
    float4 a1 = *(const float4*)(hp + k0 + 4);
    float xk[8];
    xk[0]=a0.x; xk[1]=a0.y; xk[2]=a0.z; xk[3]=a0.w;
    xk[4]=a1.x; xk[5]=a1.y; xk[6]=a1.z; xk[7]=a1.w;
#pragma unroll
    for (int kk = 0; kk < 8; ++kk) {
      const float* w = Wg1 + (size_t)(k0 + kk) * 32;
#pragma unroll
      for (int c = 0; c < 32; ++c) acc[c] = fmaf(xk[kk], w[c], acc[c]);
    }
  }
  if (row < n) {
    float g = 0.f;
#pragma unroll
    for (int c = 0; c < 32; ++c)
      g = fmaf(fmaxf(acc[c] + bg1[c], 0.f), Wg2[c], g);
    gate[row] = g + bg2[0];
  }
}

// ---------------- CSR build via bucket partition (256 dsts/bucket) ----------------
__global__ __launch_bounds__(256) void bucket_hist_kernel(const int* __restrict__ ei,
    int* __restrict__ buk_cnt, int E, int nbuk)
{
  __shared__ int h[512];
  for (int b = threadIdx.x; b < 512; b += 256) h[b] = 0;
  __syncthreads();
  int total = gridDim.x * 256;
  for (int i = blockIdx.x * 256 + threadIdx.x; i < E; i += total)
    atomicAdd(&h[((unsigned)ei[E + i]) >> 8], 1);
  __syncthreads();
  for (int b = threadIdx.x; b < nbuk; b += 256)
    if (h[b]) atomicAdd(&buk_cnt[b], h[b]);
}

__global__ __launch_bounds__(512) void scan_buckets_kernel(const int* __restrict__ buk_cnt,
    int* __restrict__ sbuk_off, int* __restrict__ buk_run, int nbuk, int E)
{
  __shared__ int lds[512];
  int t = threadIdx.x;
  int v = (t < nbuk) ? buk_cnt[t] : 0;
  lds[t] = v; __syncthreads();
  for (int off = 1; off < 512; off <<= 1) {
    int x = (t >= off) ? lds[t - off] : 0;
    __syncthreads();
    lds[t] += x;
    __syncthreads();
  }
  int excl = lds[t] - v;
  if (t < nbuk) { sbuk_off[t] = excl; buk_run[t] = excl; }
  if (t == nbuk) sbuk_off[t] = E;
}

// packed u32: src (17 bits) | dstlo (8 bits) << 17
__global__ __launch_bounds__(256) void partition_kernel(const int* __restrict__ ei,
    int* __restrict__ buk_run, unsigned* __restrict__ scratch, int E, int nbuk)
{
  __shared__ int lcnt[512];
  __shared__ int lbase[512];
  int t = threadIdx.x;
  for (int b = t; b < 512; b += 256) lcnt[b] = 0;
  __syncthreads();
  int chunk = (E + gridDim.x - 1) / gridDim.x;
  int s = blockIdx.x * chunk, e = min(E, s + chunk);
  for (int i = s + t; i < e; i += 256)
    atomicAdd(&lcnt[((unsigned)ei[E + i]) >> 8], 1);
  __syncthreads();
  for (int b = t; b < nbuk; b += 256) {
    int c = lcnt[b];
    lbase[b] = c ? atomicAdd(&buk_run[b], c) : 0;
    lcnt[b] = 0;
  }
  __syncthreads();
  for (int i = s + t; i < e; i += 256) {
    int src = ei[i];
    unsigned d = (unsigned)ei[E + i];
    int b = d >> 8;
    int r = atomicAdd(&lcnt[b], 1);
    scratch[lbase[b] + r] = (unsigned)src | ((d & 255u) << 17);
  }
}

__global__ __launch_bounds__(256) void bucket_fill_kernel(const unsigned* __restrict__ scratch,
    const int* __restrict__ sbuk_off, int* __restrict__ row_ptr,
    int* __restrict__ csr_src, int n, int nbuk)
{
  __shared__ int lcnt[256], sexcl[256], cnt2[256];
  int b = blockIdx.x, t = threadIdx.x;
  int dst0 = b << 8;
  int ndst = min(256, n - dst0);
  int s = sbuk_off[b], e = sbuk_off[b + 1];
  int base = s + dst0;
  lcnt[t] = (t < ndst) ? 1 : 0;   // +1 self-loop per dst
  __syncthreads();
  for (int i = s + t; i < e; i += 256)
    atomicAdd(&lcnt[scratch[i] >> 17], 1);
  __syncthreads();
  int c0 = lcnt[t];
  for (int off = 1; off < 256; off <<= 1) {
    int x = (t >= off) ? lcnt[t - off] : 0;
    __syncthreads();
    lcnt[t] += x;
    __syncthreads();
  }
  int ex = lcnt[t] - c0;
  sexcl[t] = ex;
  cnt2[t] = 1;
  if (t < ndst) {
    row_ptr[dst0 + t] = base + ex;
    csr_src[base + ex] = dst0 + t;        // self-loop in slot 0
  }
  if (b == nbuk - 1 && t == 0) row_ptr[n] = sbuk_off[nbuk] + n;
  __syncthreads();
  for (int i = s + t; i < e; i += 256) {
    unsigned u = scratch[i];
    int dl = u >> 17;
    int src = u & 0x1FFFF;
    int pos = base + sexcl[dl] + atomicAdd(&cnt2[dl], 1);
    csr_src[pos] = src;
  }
}

// ---------------- GATv2 layer 1: heads=2, ch=32; one wave/dst, 8 edges/iter (2x4) ----------------
// 16 lanes per edge (group g = l>>4); lane handles channels 4q..4q+3 (q = l&15).
// xl table is bf16 (ushort4 gather, exact <<16 expand).
__global__ __launch_bounds__(256) void gat1_kernel(const unsigned short* __restrict__ xl,
    const float* __restrict__ xr, const int* __restrict__ row_ptr,
    const int* __restrict__ csr_src, const float* __restrict__ att,
    const float* __restrict__ bias, float* __restrict__ hout, int n)
{
  int wid = (blockIdx.x * 256 + threadIdx.x) >> 6;
  if (wid >= n) return;
  wid = __builtin_amdgcn_readfirstlane(wid);
  int l = threadIdx.x & 63;
  int g = l >> 4;
  int q = l & 15;
  float4 xrv = *(const float4*)&xr[(size_t)wid * 64 + q * 4];
  float4 attv = *(const float4*)&att[q * 4];
  float4 attn = make_float4(attv.x * NEG_SLOPE, attv.y * NEG_SLOPE,
                            attv.z * NEG_SLOPE, attv.w * NEG_SLOPE);
  int s = row_ptr[wid], e = row_ptr[wid + 1];
  float4 accA = make_float4(0.f, 0.f, 0.f, 0.f);
  float4 accB = make_float4(0.f, 0.f, 0.f, 0.f);
  float dA = 0.f, dB = 0.f;
  for (int cb = s; cb < e; cb += 8) {
#define EDGE1(OFF, dS, aS) {                                                  \
    int idx = cb + (OFF) + g;                                                 \
    int src = csr_src[min(idx, e - 1)];                                       \
    ushort4 hv = *(const ushort4*)&xl[(size_t)src * 64 + q * 4];              \
    float4 xlv = make_float4(bf2f(hv.x), bf2f(hv.y), bf2f(hv.z), bf2f(hv.w)); \
    float tx = xlv.x + xrv.x, ty = xlv.y + xrv.y;                             \
    float tz = xlv.z + xrv.z, tw = xlv.w + xrv.w;                             \
    float v =      tx * ((tx > 0.f) ? attv.x : attn.x);                       \
    v = fmaf(ty, ((ty > 0.f) ? attv.y : attn.y), v);                          \
    v = fmaf(tz, ((tz > 0.f) ? attv.z : attn.z), v);                          \
    v = fmaf(tw, ((tw > 0.f) ? attv.w : attn.w), v);                          \
    REDUCE8(v);                                                               \
    float p = __expf(v);                                                      \
    p = (idx < e) ? p : 0.f;                                                  \
    dS += p;                                                                  \
    aS.x = fmaf(p, xlv.x, aS.x);                                              \
    aS.y = fmaf(p, xlv.y, aS.y);                                              \
    aS.z = fmaf(p, xlv.z, aS.z);                                              \
    aS.w = fmaf(p, xlv.w, aS.w); }
    EDGE1(0, dA, accA)
    EDGE1(4, dB, accB)
#undef EDGE1
  }
  float4 acc;
  acc.x = accA.x + accB.x; acc.y = accA.y + accB.y;
  acc.z = accA.z + accB.z; acc.w = accA.w + accB.w;
  float d = dA + dB;
  acc.x += __shfl_xor(acc.x, 16); acc.x += __shfl_xor(acc.x, 32);
  acc.y += __shfl_xor(acc.y, 16); acc.y += __shfl_xor(acc.y, 32);
  acc.z += __shfl_xor(acc.z, 16); acc.z += __shfl_xor(acc.z, 32);
  acc.w += __shfl_xor(acc.w, 16); acc.w += __shfl_xor(acc.w, 32);
  d += __shfl_xor(d, 16); d += __shfl_xor(d, 32);
  if (g == 0) {
    float inv = 1.f / (d + 1e-16f);
    float4 b4 = *(const float4*)&bias[q * 4];
    float4 o;
    o.x = fmaxf(fmaf(acc.x, inv, b4.x), 0.f);
    o.y = fmaxf(fmaf(acc.y, inv, b4.y), 0.f);
    o.z = fmaxf(fmaf(acc.z, inv, b4.z), 0.f);
    o.w = fmaxf(fmaf(acc.w, inv, b4.w), 0.f);
    *(float4*)&hout[(size_t)wid * 64 + q * 4] = o;
  }
}

// ---------------- GATv2 layer 2: heads=1, ch=32; one wave/dst, 16 edges/iter (2x8) ----------------
// 8 lanes per edge (group g8 = l>>3); lane handles channels 4q..4q+3 (q = l&7).  bf16 xl.
__global__ __launch_bounds__(256) void gat2_kernel(const unsigned short* __restrict__ xl,
    const float* __restrict__ xr, const int* __restrict__ row_ptr,
    const int* __restrict__ csr_src, const float* __restrict__ att,
    const float* __restrict__ bias, float* __restrict__ hout, int n)
{
  int wid = (blockIdx.x * 256 + threadIdx.x) >> 6;
  if (wid >= n) return;
  wid = __builtin_amdgcn_readfirstlane(wid);
  int l = threadIdx.x & 63;
  int g8 = l >> 3;
  int q = l & 7;
  float4 xrv = *(const float4*)&xr[(size_t)wid * 32 + q * 4];
  float4 attv = *(const float4*)&att[q * 4];
  float4 attn = make_float4(attv.x * NEG_SLOPE, attv.y * NEG_SLOPE,
                            attv.z * NEG_SLOPE, attv.w * NEG_SLOPE);
  int s = row_ptr[wid], e = row_ptr[wid + 1];
  int deg = e - s;
  float4 accA = make_float4(0.f, 0.f, 0.f, 0.f);
  float4 accB = make_float4(0.f, 0.f, 0.f, 0.f);
  float dA = 0.f, dB = 0.f;
  for (int i0 = 0; i0 < deg; i0 += 16) {
#define EDGE2(OFF, dS, aS) {                                                  \
    int ii = i0 + (OFF) + g8;                                                 \
    int src = csr_src[s + min(ii, deg - 1)];                                  \
    ushort4 hv = *(const ushort4*)&xl[(size_t)src * 32 + q * 4];              \
    float4 xlv = make_float4(bf2f(hv.x), bf2f(hv.y), bf2f(hv.z), bf2f(hv.w)); \
    float tx = xlv.x + xrv.x, ty = xlv.y + xrv.y;                             \
    float tz = xlv.z + xrv.z, tw = xlv.w + xrv.w;                             \
    float v =      tx * ((tx > 0.f) ? attv.x : attn.x);                       \
    v = fmaf(ty, ((ty > 0.f) ? attv.y : attn.y), v);                          \
    v = fmaf(tz, ((tz > 0.f) ? attv.z : attn.z), v);                          \
    v = fmaf(tw, ((tw > 0.f) ? attv.w : attn.w), v);                          \
    REDUCE8(v);                                                               \
    float p = __expf(v);                                                      \
    p = (ii < deg) ? p : 0.f;                                                 \
    dS += p;                                                                  \
    aS.x = fmaf(p, xlv.x, aS.x);                                              \
    aS.y = fmaf(p, xlv.y, aS.y);                                              \
    aS.z = fmaf(p, xlv.z, aS.z);                                              \
    aS.w = fmaf(p, xlv.w, aS.w); }
    EDGE2(0, dA, accA)
    EDGE2(8, dB, accB)
#undef EDGE2
  }
  float4 acc;
  acc.x = accA.x + accB.x; acc.y = accA.y + accB.y;
  acc.z = accA.z + accB.z; acc.w = accA.w + accB.w;
  float d = dA + dB;
  acc.x += __shfl_xor(acc.x, 8); acc.x += __shfl_xor(acc.x, 16); acc.x += __shfl_xor(acc.x, 32);
  acc.y += __shfl_xor(acc.y, 8); acc.y += __shfl_xor(acc.y, 16); acc.y += __shfl_xor(acc.y, 32);
  acc.z += __shfl_xor(acc.z, 8); acc.z += __shfl_xor(acc.z, 16); acc.z += __shfl_xor(acc.z, 32);
  acc.w += __shfl_xor(acc.w, 8); acc.w += __shfl_xor(acc.w, 16); acc.w += __shfl_xor(acc.w, 32);
  d += __shfl_xor(d, 8); d += __shfl_xor(d, 16); d += __shfl_xor(d, 32);
  if (g8 == 0) {
    float inv = 1.f / (d + 1e-16f);
    float4 b4 = *(const float4*)&bias[q * 4];
    float4 o;
    o.x = fmaxf(fmaf(acc.x, inv, b4.x), 0.f);
    o.y = fmaxf(fmaf(acc.y, inv, b4.y), 0.f);
    o.z = fmaxf(fmaf(acc.z, inv, b4.z), 0.f);
    o.w = fmaxf(fmaf(acc.w, inv, b4.w), 0.f);
    *(float4*)&hout[(size_t)wid * 32 + q * 4] = o;
  }
}

// ---------------- per-graph softmax pooling + head MLP ----------------
__global__ __launch_bounds__(1024) void pool_head_kernel(const float* __restrict__ h2,
    const float* __restrict__ gate, const int* __restrict__ batch,
    const float* __restrict__ W1, const float* __restrict__ b1,
    const float* __restrict__ W2, const float* __restrict__ b2,
    float* __restrict__ out, int n)
{
  int g = blockIdx.x;
  int t = threadIdx.x;
  int lo = 0, hi = n;
  while (lo < hi) { int mid = (lo + hi) >> 1; if (batch[mid] < g) lo = mid + 1; else hi = mid; }
  int s = lo;
  lo = s; hi = n;
  while (lo < hi) { int mid = (lo + hi) >> 1; if (batch[mid] < g + 1) lo = mid + 1; else hi = mid; }
  int e = lo;

  __shared__ float red[1024];
  float lm = -INFINITY;
  for (int i = s + t; i < e; i += 1024) lm = fmaxf(lm, gate[i]);
  red[t] = lm; __syncthreads();
  for (int off = 512; off > 0; off >>= 1) {
    if (t < off) red[t] = fmaxf(red[t], red[t + off]);
    __syncthreads();
  }
  float m = (s == e) ? 0.f : red[0];
  __syncthreads();

  int c = t & 31, grp = t >> 5;        // 32 node-groups x 32 channels
  float acc = 0.f, dsum = 0.f;
  for (int i = s + grp; i < e; i += 32) {
    float sv = __expf(gate[i] - m);
    acc += sv * h2[(size_t)i * 32 + c];
    if (c == 0) dsum += sv;
  }
  __shared__ float accs[32][33];
  __shared__ float dss[32];
  accs[grp][c] = acc;
  if (c == 0) dss[grp] = dsum;
  __syncthreads();

  if (t < 32) {
    float a = 0.f, dd = 0.f;
#pragma unroll
    for (int k = 0; k < 32; ++k) { a += accs[k][t]; dd += dss[k]; }
    float p = a / (dd + 1e-16f);
    float q = 0.f;
    for (int cc = 0; cc < 32; ++cc)
      q = fmaf(__shfl(p, cc, 32), W1[cc * 32 + t], q);
    q = fmaxf(q + b1[t], 0.f);
    float r = q * W2[t];
    r += __shfl_xor(r, 1, 32);  r += __shfl_xor(r, 2, 32);
    r += __shfl_xor(r, 4, 32);  r += __shfl_xor(r, 8, 32);
    r += __shfl_xor(r, 16, 32);
    if (t == 0) out[g] = r + b2[0];
  }
}

// ---------------- host ----------------
extern "C" void kernel_launch(void* const* d_in, const int* in_sizes, int n_in,
                              void* d_out, int out_size, void* d_ws, size_t ws_size,
                              hipStream_t stream)
{
  const float* x     = (const float*)d_in[0];
  const int*   ei    = (const int*)d_in[1];
  const int*   batch = (const int*)d_in[2];
  const float* Wl1   = (const float*)d_in[3];
  const float* bl1   = (const float*)d_in[4];
  const float* Wr1   = (const float*)d_in[5];
  const float* br1   = (const float*)d_in[6];
  const float* att1  = (const float*)d_in[7];
  const float* bias1 = (const float*)d_in[8];
  const float* Wl2   = (const float*)d_in[9];
  const float* bl2   = (const float*)d_in[10];
  const float* Wr2   = (const float*)d_in[11];
  const float* br2   = (const float*)d_in[12];
  const float* att2  = (const float*)d_in[13];
  const float* bias2 = (const float*)d_in[14];
  const float* Wg1   = (const float*)d_in[15];
  const float* bg1   = (const float*)d_in[16];
  const float* Wg2   = (const float*)d_in[17];
  const float* bg2   = (const float*)d_in[18];
  const float* W1    = (const float*)d_in[19];
  const float* b1    = (const float*)d_in[20];
  const float* W2    = (const float*)d_in[21];
  const float* b2    = (const float*)d_in[22];
  float* out = (float*)d_out;

  const int n = in_sizes[2];
  const int E = in_sizes[1] / 2;
  const int nbuk = (n + 255) / 256;   // 391 for n=100k (<=511 required)

  float* fws = (float*)d_ws;
  size_t nf64 = (size_t)n * 64;
  float* bufA = fws;                      // xl1(bf16) -> xl2(bf16)|xr2(f32)
  float* bufB = bufA + nf64;              // xr1 -> h2 | gate
  float* bufC = bufB + nf64;              // partition scratch during build, then h
  unsigned short* xl1 = (unsigned short*)bufA;      // n*64 bf16
  float* xr1 = bufB;                                 // n*64 f32
  float* hbuf = bufC;                                // n*64 f32
  unsigned short* xl2 = (unsigned short*)bufA;       // n*32 bf16
  float* xr2 = bufA + (size_t)n * 16;                // n*32 f32 (after n*32 bf16 = n*16 floats)
  float* h2  = bufB;                                 // n*32 f32
  float* gate = bufB + (size_t)n * 32;               // n f32
  unsigned* scratch = (unsigned*)bufC;    // E u32, dead before gat1 writes hbuf
  int* ip       = (int*)(bufC + nf64);
  int* row_ptr  = ip;  ip += (n + 2);
  int* buk_cnt  = ip;  ip += 512;
  int* sbuk_off = ip;  ip += 520;
  int* buk_run  = ip;  ip += 512;
  int* csr_src  = ip;                     // E + n ints

  hipMemsetAsync(buk_cnt, 0, 512 * sizeof(int), stream);

  int mb32 = (n + 31) / 32;   // 32-row GEMM tiles

  mm_dual_kernel<128, 64><<<mb32, 256, 0, stream>>>(x, Wl1, bl1, Wr1, br1, xl1, xr1, n);

  bucket_hist_kernel<<<256, 256, 0, stream>>>(ei, buk_cnt, E, nbuk);
  scan_buckets_kernel<<<1, 512, 0, stream>>>(buk_cnt, sbuk_off, buk_run, nbuk, E);
  partition_kernel<<<256, 256, 0, stream>>>(ei, buk_run, scratch, E, nbuk);
  bucket_fill_kernel<<<nbuk, 256, 0, stream>>>(scratch, sbuk_off, row_ptr, csr_src, n, nbuk);

  int gatblocks = (n + 3) / 4;   // 4 waves (dsts) per block
  gat1_kernel<<<gatblocks, 256, 0, stream>>>(xl1, xr1, row_ptr, csr_src, att1, bias1, hbuf, n);

  mm_dual_kernel<64, 32><<<mb32, 256, 0, stream>>>(hbuf, Wl2, bl2, Wr2, br2, xl2, xr2, n);

  gat2_kernel<<<gatblocks, 256, 0, stream>>>(xl2, xr2, row_ptr, csr_src, att2, bias2, h2, n);

  gate_kernel<<<(n + 255) / 256, 256, 0, stream>>>(h2, Wg1, bg1, Wg2, bg2, gate, n);

  pool_head_kernel<<<64, 1024, 0, stream>>>(h2, gate, batch, W1, b1, W2, b2, out, n);
}